// Round 8
// baseline (50.293 us; speedup 1.0000x reference)
//
#include <hip/hip_runtime.h>
#include <hip/hip_bf16.h>

typedef float f32x16 __attribute__((ext_vector_type(16)));
typedef float f32x4v __attribute__((ext_vector_type(4)));

#define GLOBAL_AS(p) ((const __attribute__((address_space(1))) void*)(p))
#define LDS_AS(p)    ((__attribute__((address_space(3))) void*)(p))

#define LP 8192
#define D 128
#define TWOEPS 2e-6f
#define CEPS 1.28e-10f   /* 128 * EPS^2 */
#define MARGIN 0.2f
#define NTRI 2080        /* 64*65/2 lower-triangular 128x128 tiles */
#define NBLK 512
#define INV_DENOM 1.4903545e-8f  /* 1 / (8192*8191) */

/* LDS per buffer: A panels 16K | B panels 16K | QW (i 1K, j 1K) */
#define BUFSZ 34816
#define AOFF 0
#define BOFF 16384
#define QWOFF 32768

// ---------------- Phase A: normalize p rows -> fp8, write qw = (q8, w) -------------
// 4 lanes per row, 16 rows per wave. Block 0 also zeroes out[0] and the tile counter.
__global__ __launch_bounds__(64) void rows_kernel(const float* __restrict__ p,
                                                  const float* __restrict__ n,
                                                  char* __restrict__ pb,
                                                  float* __restrict__ qw,
                                                  int* __restrict__ ctr,
                                                  float* __restrict__ out) {
    const int lane = threadIdx.x;
    if (blockIdx.x == 0 && lane == 0) { out[0] = 0.0f; ctr[0] = 0; }
    const int sub = lane & 3;    // quarter of the row (32 floats)
    const int r = lane >> 2;     // 0..15
    const int row = blockIdx.x * 16 + r;

    const float4* px = (const float4*)(p + (size_t)row * D + sub * 32);
    const float4* nx = (const float4*)(n + sub * 32);  // n row 0 (t=0)
    float4 x[8], y[8];
#pragma unroll
    for (int k = 0; k < 8; ++k) { x[k] = px[k]; y[k] = nx[k]; }

    float ssp = 0.0f, ssn = 0.0f;
#pragma unroll
    for (int k = 0; k < 8; ++k) {
        ssp += fmaf(x[k].x, x[k].x, fmaf(x[k].y, x[k].y,
               fmaf(x[k].z, x[k].z, x[k].w * x[k].w)));
        ssn += fmaf(y[k].x, y[k].x, fmaf(y[k].y, y[k].y,
               fmaf(y[k].z, y[k].z, y[k].w * y[k].w)));
    }
    ssp += __shfl_xor(ssp, 1); ssp += __shfl_xor(ssp, 2);
    ssn += __shfl_xor(ssn, 1); ssn += __shfl_xor(ssn, 2);

    const float invp = 1.0f / fmaxf(sqrtf(ssp), 1e-12f);
    const float invn = 1.0f / fmaxf(sqrtf(ssn), 1e-12f);

    float s = 0.0f, q = 0.0f, dn = 0.0f, sn = 0.0f, qn = 0.0f, q8 = 0.0f;
    int pk8[8];
#pragma unroll
    for (int k = 0; k < 8; ++k) {
        float a0 = x[k].x * invp, a1 = x[k].y * invp,
              a2 = x[k].z * invp, a3 = x[k].w * invp;
        float h0 = y[k].x * invn, h1 = y[k].y * invn,
              h2 = y[k].z * invn, h3 = y[k].w * invn;
        s  += (a0 + a1) + (a2 + a3);
        q  += fmaf(a0, a0, fmaf(a1, a1, fmaf(a2, a2, a3 * a3)));
        dn += fmaf(a0, h0, fmaf(a1, h1, fmaf(a2, h2, a3 * h3)));
        sn += (h0 + h1) + (h2 + h3);
        qn += fmaf(h0, h0, fmaf(h1, h1, fmaf(h2, h2, h3 * h3)));
        int wlo = __builtin_amdgcn_cvt_pk_fp8_f32(a0, a1, 0, false);
        int wfl = __builtin_amdgcn_cvt_pk_fp8_f32(a2, a3, wlo, true);
        pk8[k] = wfl;
        float b0 = __builtin_amdgcn_cvt_f32_fp8(wfl, 0);
        float b1 = __builtin_amdgcn_cvt_f32_fp8(wfl, 1);
        float b2 = __builtin_amdgcn_cvt_f32_fp8(wfl, 2);
        float b3 = __builtin_amdgcn_cvt_f32_fp8(wfl, 3);
        q8 += fmaf(b0, b0, fmaf(b1, b1, fmaf(b2, b2, b3 * b3)));
    }
    char* dst = pb + (size_t)row * 128 + sub * 32;
    ((int4*)dst)[0] = make_int4(pk8[0], pk8[1], pk8[2], pk8[3]);
    ((int4*)dst)[1] = make_int4(pk8[4], pk8[5], pk8[6], pk8[7]);

#pragma unroll
    for (int m = 1; m < 4; m <<= 1) {
        s += __shfl_xor(s, m);
        q += __shfl_xor(q, m);
        dn += __shfl_xor(dn, m);
        sn += __shfl_xor(sn, m);
        qn += __shfl_xor(qn, m);
        q8 += __shfl_xor(q8, m);
    }
    if (sub == 0) {
        float sq = q + qn - 2.0f * dn + TWOEPS * (s - sn) + CEPS;
        float dpn = sqrtf(fmaxf(sq, 0.0f));
        *(float2*)(qw + (size_t)row * 2) = make_float2(q8, MARGIN - dpn);
    }
}

// ---------------- Phase B: persistent, work-stealing, panel-layout pair kernel ------
// LDS A/B tiles stored as K-panels [chunk 0..7][row 0..127][16 B]: fragment
// ds_read_b64 across rows is stride-16B -> conflict-free. Staging is
// global(row-major, coalesced) -> registers -> ds_write_b128 (floor-rate).
// Double-buffered, one __syncthreads per tile; next tile's loads issued before
// compute so HBM/L2 latency hides under MFMA+epilogue. Tiles grabbed from a
// global counter (balanced +-1 across CUs).
__global__ __launch_bounds__(512, 4) void pair_kernel(const char* __restrict__ pb,
                                                      const float* __restrict__ qw,
                                                      int* __restrict__ ctr,
                                                      float* __restrict__ out) {
    __shared__ __align__(16) char smem[2 * BUFSZ + 16];
    int* slot = (int*)(smem + 2 * BUFSZ);

    const int tid = threadIdx.x;
    const int wave = tid >> 6, lane = tid & 63;
    const int wr = wave >> 2, wc = wave & 3;  // 2x4 waves, 64x32 output each
    const int ln31 = lane & 31;
    const int h = lane >> 5;

    auto decode = [](int b, int& ti, int& tj) {
        int t = (int)((__builtin_amdgcn_sqrtf(8.0f * (float)b + 1.0f) - 1.0f) * 0.5f);
        while ((t + 1) * (t + 2) / 2 <= b) ++t;
        while (t * (t + 1) / 2 > b) --t;
        ti = t;
        tj = b - t * (t + 1) / 2;
    };

    // issue next tile's loads: A/B rows -> registers, qw -> LDS (direct DMA)
    auto issue = [&](int idx, char* buf, int4* ra, int4* rb) {
        int ti, tj;
        decode(idx, ti, tj);
        const char* gA = pb + (size_t)ti * 16384;
        const char* gB = pb + (size_t)tj * 16384;
#pragma unroll
        for (int r = 0; r < 2; ++r) {
            int o = wave * 2048 + r * 1024 + lane * 16;
            ra[r] = *(const int4*)(gA + o);
            rb[r] = *(const int4*)(gB + o);
        }
        int side = wave >> 2, chunk = wave & 3;
        const char* gq = (const char*)qw + (size_t)(side ? tj : ti) * 1024 +
                         chunk * 256 + lane * 4;
        __builtin_amdgcn_global_load_lds(GLOBAL_AS(gq),
                                         LDS_AS(buf + QWOFF + side * 1024 + chunk * 256),
                                         4, 0, 0);
    };

    // write staged registers into K-panel layout
    auto writep = [&](char* buf, int4* ra, int4* rb) {
#pragma unroll
        for (int r = 0; r < 2; ++r) {
            int c = lane & 7;
            int row = wave * 16 + r * 8 + (lane >> 3);
            *(int4*)(buf + AOFF + c * 2048 + row * 16) = ra[r];
            *(int4*)(buf + BOFF + c * 2048 + row * 16) = rb[r];
        }
    };

    // prologue: grab first tile
    if (tid == 0) *slot = atomicAdd(ctr, 1);
    __syncthreads();
    int icur = *slot;
    bool vcur = icur < NTRI;

    int4 ra[2], rb[2];
    if (vcur) {
        issue(icur, smem, ra, rb);
        writep(smem, ra, rb);
    }
    if (tid == 0) *slot = atomicAdd(ctr, 1);
    __syncthreads();  // panels + qw(buf0) visible, slot visible
    int inxt = *slot;

    float la0 = 0.0f, la1 = 0.0f, lb0 = 0.0f, lb1 = 0.0f;
    int cur = 0;

    while (vcur) {
        char* bufc = smem + (size_t)cur * BUFSZ;
        char* bufn = smem + (size_t)(cur ^ 1) * BUFSZ;
        bool vnxt = inxt < NTRI;
        if (vnxt) issue(inxt, bufn, ra, rb);  // latency hides under compute below

        int ti, tj;
        decode(icur, ti, tj);
        const bool diag = (ti == tj);

        const char* lA = bufc + AOFF;
        const char* lB = bufc + BOFF;
        const float* qwi = (const float*)(bufc + QWOFF);
        const float* qwj = (const float*)(bufc + QWOFF + 1024);

        f32x16 acc[2] = {};
#pragma unroll
        for (int ks = 0; ks < 8; ++ks) {
            int ko = ks * 2048 + h * 8;
            long bv = *(const long*)(lB + ko + (wc * 32 + ln31) * 16);
#pragma unroll
            for (int mt = 0; mt < 2; ++mt) {
                long av = *(const long*)(lA + ko + (wr * 64 + mt * 32 + ln31) * 16);
                acc[mt] = __builtin_amdgcn_mfma_f32_32x32x16_fp8_fp8(av, bv, acc[mt],
                                                                     0, 0, 0);
            }
        }

        // Epilogue. C/D 32x32: col = ln31, row = (reg&3) + 8*(reg>>2) + 4*h.
        float2 qwjv = *(const float2*)(qwj + (wc * 32 + ln31) * 2);
        if (diag) {
#pragma unroll
            for (int mt = 0; mt < 2; ++mt)
#pragma unroll
                for (int g = 0; g < 4; ++g) {
                    int rbase = wr * 64 + mt * 32 + 8 * g + 4 * h;
                    f32x4v qw01 = *(const f32x4v*)(qwi + rbase * 2);
                    f32x4v qw23 = *(const f32x4v*)(qwi + rbase * 2 + 4);
                    float qi[4] = {qw01[0], qw01[2], qw23[0], qw23[2]};
                    float wi[4] = {qw01[1], qw01[3], qw23[1], qw23[3]};
#pragma unroll
                    for (int r2 = 0; r2 < 4; ++r2) {
                        float sq = fmaf(-2.0f, acc[mt][g * 4 + r2], qi[r2] + qwjv.x);
                        float d = __builtin_amdgcn_sqrtf(fmaxf(sq, 0.0f));
                        if (mt) la1 += fmaxf(d + wi[r2], 0.0f);
                        else    la0 += fmaxf(d + wi[r2], 0.0f);
                    }
                }
        } else {
#pragma unroll
            for (int mt = 0; mt < 2; ++mt)
#pragma unroll
                for (int g = 0; g < 4; ++g) {
                    int rbase = wr * 64 + mt * 32 + 8 * g + 4 * h;
                    f32x4v qw01 = *(const f32x4v*)(qwi + rbase * 2);
                    f32x4v qw23 = *(const f32x4v*)(qwi + rbase * 2 + 4);
                    float qi[4] = {qw01[0], qw01[2], qw23[0], qw23[2]};
                    float wi[4] = {qw01[1], qw01[3], qw23[1], qw23[3]};
#pragma unroll
                    for (int r2 = 0; r2 < 4; ++r2) {
                        float sq = fmaf(-2.0f, acc[mt][g * 4 + r2], qi[r2] + qwjv.x);
                        float d = __builtin_amdgcn_sqrtf(sq);  // off-diag: sq >= ~0.9
                        if (mt) { la1 += fmaxf(d + wi[r2], 0.0f);
                                  lb1 += fmaxf(d + qwjv.y, 0.0f); }
                        else    { la0 += fmaxf(d + wi[r2], 0.0f);
                                  lb0 += fmaxf(d + qwjv.y, 0.0f); }
                    }
                }
        }

        if (vnxt) writep(bufn, ra, rb);  // compiler waits the reg loads here
        if (tid == 0) *slot = atomicAdd(ctr, 1);
        __syncthreads();  // drains vmcnt+lgkm: panels/qw(bufn) ready, slot visible
        icur = inxt;
        vcur = vnxt;
        inxt = *slot;
        cur ^= 1;
    }

    // block reduction (order fixed within block) + one atomic per block
    float local = (la0 + la1) + (lb0 + lb1);
#pragma unroll
    for (int m = 1; m < 64; m <<= 1) local += __shfl_xor(local, m);
    float* sred = (float*)smem;
    if (lane == 0) sred[wave] = local;
    __syncthreads();
    if (tid == 0) {
        float t0 = (sred[0] + sred[1]) + (sred[2] + sred[3]);
        float t1 = (sred[4] + sred[5]) + (sred[6] + sred[7]);
        atomicAdd(out, (t0 + t1) * INV_DENOM);
    }
}

extern "C" void kernel_launch(void* const* d_in, const int* in_sizes, int n_in,
                              void* d_out, int out_size, void* d_ws, size_t ws_size,
                              hipStream_t stream) {
    const float* p = (const float*)d_in[0];  // [8192,128] f32
    const float* n = (const float*)d_in[1];  // [64,128] f32
    float* out = (float*)d_out;
    char* ws = (char*)d_ws;

    // ws layout
    char*  pb    = ws;                                      // 1 MB (8192 x 128 B fp8)
    float* qwarr = (float*)(ws + (1u << 20));               // 64 KB (8192 x float2)
    int*   ctr   = (int*)(ws + (1u << 20) + (64u << 10));   // 4 B tile counter

    hipLaunchKernelGGL(rows_kernel, dim3(LP / 16), dim3(64), 0, stream, p, n, pb, qwarr,
                       ctr, out);
    hipLaunchKernelGGL(pair_kernel, dim3(NBLK), dim3(512), 0, stream, pb, qwarr, ctr, out);
}

// Round 9
// 33.256 us; speedup vs baseline: 1.5123x; 1.5123x over previous
//
#include <hip/hip_runtime.h>
#include <hip/hip_bf16.h>

typedef float f32x16 __attribute__((ext_vector_type(16)));
typedef float f32x4v __attribute__((ext_vector_type(4)));

#define GLOBAL_AS(p) ((const __attribute__((address_space(1))) void*)(p))
#define LDS_AS(p)    ((__attribute__((address_space(3))) void*)(p))

#define LP 8192
#define D 128
#define TWOEPS 2e-6f
#define CEPS 1.28e-10f   /* 128 * EPS^2 */
#define MARGIN 0.2f
#define NTRI 2080        /* 64*65/2 tiles; superrow s pairs rows s and 63-s (65 tiles) */
#define NBLK 512
#define INV_DENOM 1.4903545e-8f  /* 1 / (8192*8191) */

#define TILEB 16384
#define BQ (TILEB + 1024)
/* smem: A0 16K | A1 16K | B0 16K+1K | B1 16K+1K  = 67584 B -> 2 blocks/CU */
#define A0OFF 0
#define A1OFF 16384
#define B0OFF 32768
#define B1OFF (32768 + BQ)

// ---------------- Phase A: normalize p rows -> fp8, write qw = (q8, w) -------------
__global__ __launch_bounds__(64) void rows_kernel(const float* __restrict__ p,
                                                  const float* __restrict__ n,
                                                  char* __restrict__ pb,
                                                  float* __restrict__ qw,
                                                  float* __restrict__ out) {
    const int lane = threadIdx.x;
    if (blockIdx.x == 0 && lane == 0) out[0] = 0.0f;
    const int sub = lane & 3;    // quarter of the row (32 floats)
    const int r = lane >> 2;     // 0..15
    const int row = blockIdx.x * 16 + r;

    const float4* px = (const float4*)(p + (size_t)row * D + sub * 32);
    const float4* nx = (const float4*)(n + sub * 32);  // n row 0 (t=0)
    float4 x[8], y[8];
#pragma unroll
    for (int k = 0; k < 8; ++k) { x[k] = px[k]; y[k] = nx[k]; }

    float ssp = 0.0f, ssn = 0.0f;
#pragma unroll
    for (int k = 0; k < 8; ++k) {
        ssp += fmaf(x[k].x, x[k].x, fmaf(x[k].y, x[k].y,
               fmaf(x[k].z, x[k].z, x[k].w * x[k].w)));
        ssn += fmaf(y[k].x, y[k].x, fmaf(y[k].y, y[k].y,
               fmaf(y[k].z, y[k].z, y[k].w * y[k].w)));
    }
    ssp += __shfl_xor(ssp, 1); ssp += __shfl_xor(ssp, 2);
    ssn += __shfl_xor(ssn, 1); ssn += __shfl_xor(ssn, 2);

    const float invp = 1.0f / fmaxf(sqrtf(ssp), 1e-12f);
    const float invn = 1.0f / fmaxf(sqrtf(ssn), 1e-12f);

    float s = 0.0f, q = 0.0f, dn = 0.0f, sn = 0.0f, qn = 0.0f, q8 = 0.0f;
    int pk8[8];
#pragma unroll
    for (int k = 0; k < 8; ++k) {
        float a0 = x[k].x * invp, a1 = x[k].y * invp,
              a2 = x[k].z * invp, a3 = x[k].w * invp;
        float h0 = y[k].x * invn, h1 = y[k].y * invn,
              h2 = y[k].z * invn, h3 = y[k].w * invn;
        s  += (a0 + a1) + (a2 + a3);
        q  += fmaf(a0, a0, fmaf(a1, a1, fmaf(a2, a2, a3 * a3)));
        dn += fmaf(a0, h0, fmaf(a1, h1, fmaf(a2, h2, a3 * h3)));
        sn += (h0 + h1) + (h2 + h3);
        qn += fmaf(h0, h0, fmaf(h1, h1, fmaf(h2, h2, h3 * h3)));
        int wlo = __builtin_amdgcn_cvt_pk_fp8_f32(a0, a1, 0, false);
        int wfl = __builtin_amdgcn_cvt_pk_fp8_f32(a2, a3, wlo, true);
        pk8[k] = wfl;
        float b0 = __builtin_amdgcn_cvt_f32_fp8(wfl, 0);
        float b1 = __builtin_amdgcn_cvt_f32_fp8(wfl, 1);
        float b2 = __builtin_amdgcn_cvt_f32_fp8(wfl, 2);
        float b3 = __builtin_amdgcn_cvt_f32_fp8(wfl, 3);
        q8 += fmaf(b0, b0, fmaf(b1, b1, fmaf(b2, b2, b3 * b3)));
    }
    char* dst = pb + (size_t)row * 128 + sub * 32;
    ((int4*)dst)[0] = make_int4(pk8[0], pk8[1], pk8[2], pk8[3]);
    ((int4*)dst)[1] = make_int4(pk8[4], pk8[5], pk8[6], pk8[7]);

#pragma unroll
    for (int m = 1; m < 4; m <<= 1) {
        s += __shfl_xor(s, m);
        q += __shfl_xor(q, m);
        dn += __shfl_xor(dn, m);
        sn += __shfl_xor(sn, m);
        qn += __shfl_xor(qn, m);
        q8 += __shfl_xor(q8, m);
    }
    if (sub == 0) {
        float sq = q + qn - 2.0f * dn + TWOEPS * (s - sn) + CEPS;
        float dpn = sqrtf(fmaxf(sq, 0.0f));
        *(float2*)(qw + (size_t)row * 2) = make_float2(q8, MARGIN - dpn);
    }
}

// ---------------- Phase B: superrow-scheduled double-buffered pair kernel ----------
// Tile g: superrow s=g/65, pos=g%65; pos<=s -> (ti=s, tj=pos) else (63-s, pos-s-1).
// Consecutive g share ti in runs -> A staged ~1.5x/block; qi/wi cached in regs.
// Per tile: stage B(next) [2 gload_lds] + qwj [1 gload_lds]; vmcnt(3) (5 on A-change);
// barrier; MFMA from LDS (XOR chunk swizzle = b64 bandwidth floor); epilogue; barrier.
__global__ __launch_bounds__(512, 4) void pair_kernel(const char* __restrict__ pb,
                                                      const float* __restrict__ qw,
                                                      float* __restrict__ out) {
    __shared__ __align__(16) char smem[2 * TILEB + 2 * BQ];
    const int tid = threadIdx.x;
    const int wave = tid >> 6, lane = tid & 63;
    const int wr = wave >> 2, wc = wave & 3;  // 2x4 waves, 64x32 output each
    const int ln31 = lane & 31;
    const int h = lane >> 5;
    const int blk = blockIdx.x;

    const int g0 = blk * 4 + (blk < 32 ? blk : 32);
    const int nt = (blk < 32) ? 5 : 4;

    auto decode = [](int g, int& ti, int& tj) {
        int s = g / 65;
        int pos = g - s * 65;
        if (pos <= s) { ti = s; tj = pos; }
        else          { ti = 63 - s; tj = pos - s - 1; }
    };

    auto stageT = [&](int tt, char* buf) {  // 16KB tile, 2 loads/wave
#pragma unroll
        for (int r = 0; r < 2; ++r) {
            int o = wave * 2048 + r * 1024;
            int ol = o + lane * 16;
            int src = ol ^ (((ol >> 7) & 7) << 4);  // inverse swizzle on global side
            __builtin_amdgcn_global_load_lds(GLOBAL_AS(pb + (size_t)tt * TILEB + src),
                                             LDS_AS(buf + o), 16, 0, 0);
        }
    };
    auto stageQ = [&](int tj, char* buf) {  // 1KB qwj, 1 load/wave (lanes 0-31)
        if (lane < 32)
            __builtin_amdgcn_global_load_lds(
                GLOBAL_AS((const char*)qw + (size_t)tj * 1024 + wave * 128 + lane * 4),
                LDS_AS(buf + TILEB + wave * 128), 4, 0, 0);
    };

    int ti0, tj0;
    decode(g0, ti0, tj0);
    stageT(ti0, smem + A0OFF);
    stageT(tj0, smem + B0OFF);
    stageQ(tj0, smem + B0OFF);
    int apar = 0;        // bufA[apar] holds current ti
    int tiLoaded = -1;   // which ti the qi/wi register cache holds
    float qi[2][4][4], wi[2][4][4];  // statically-indexed register cache (64 f32)
    float la0 = 0.0f, la1 = 0.0f, lb0 = 0.0f, lb1 = 0.0f;

    for (int t = 0; t < nt; ++t) {
        int ti, tj;
        decode(g0 + t, ti, tj);
        bool chA = false;
        if (t + 1 < nt) {
            int ti1, tj1;
            decode(g0 + t + 1, ti1, tj1);
            chA = (ti1 != ti);
            char* bn = smem + (((t + 1) & 1) ? B1OFF : B0OFF);
            stageT(tj1, bn);
            stageQ(tj1, bn);
            if (chA) {
                stageT(ti1, smem + ((apar ^ 1) ? A1OFF : A0OFF));
                asm volatile("s_waitcnt vmcnt(5)" ::: "memory");  // cur tile's 3 landed
            } else {
                asm volatile("s_waitcnt vmcnt(3)" ::: "memory");
            }
        } else {
            asm volatile("s_waitcnt vmcnt(0)" ::: "memory");
        }
        __builtin_amdgcn_s_barrier();
        __builtin_amdgcn_sched_barrier(0);

        // refresh i-side scalar cache on A-change (uniform branch; latency hides
        // under the MFMA phase below; next manual vmcnt also covers these)
        if (ti != tiLoaded) {
            tiLoaded = ti;
            const float* qwi = qw + (size_t)ti * 256;
#pragma unroll
            for (int mt = 0; mt < 2; ++mt)
#pragma unroll
                for (int g = 0; g < 4; ++g) {
                    int rbase = wr * 64 + mt * 32 + 8 * g + 4 * h;
                    f32x4v a = *(const f32x4v*)(qwi + rbase * 2);
                    f32x4v b = *(const f32x4v*)(qwi + rbase * 2 + 4);
                    qi[mt][g][0] = a[0]; wi[mt][g][0] = a[1];
                    qi[mt][g][1] = a[2]; wi[mt][g][1] = a[3];
                    qi[mt][g][2] = b[0]; wi[mt][g][2] = b[1];
                    qi[mt][g][3] = b[2]; wi[mt][g][3] = b[3];
                }
        }

        const char* lA = smem + (apar ? A1OFF : A0OFF);
        const char* lB = smem + ((t & 1) ? B1OFF : B0OFF);

        f32x16 acc0 = {}, acc1 = {};
#pragma unroll
        for (int ks = 0; ks < 8; ++ks) {
            int co = ((ks ^ (ln31 & 7)) << 4) + h * 8;
            long bv  = *(const long*)(lB + (wc * 32 + ln31) * 128 + co);
            long av0 = *(const long*)(lA + (wr * 64 + ln31) * 128 + co);
            long av1 = *(const long*)(lA + (wr * 64 + 32 + ln31) * 128 + co);
            acc0 = __builtin_amdgcn_mfma_f32_32x32x16_fp8_fp8(av0, bv, acc0, 0, 0, 0);
            acc1 = __builtin_amdgcn_mfma_f32_32x32x16_fp8_fp8(av1, bv, acc1, 0, 0, 0);
        }

        // Epilogue. C/D 32x32: col = ln31, row = (reg&3) + 8*(reg>>2) + 4*h.
        float2 qwjv = *(const float2*)(lB + TILEB + (wc * 32 + ln31) * 8);
        const bool diag = (ti == tj);
#pragma unroll
        for (int g = 0; g < 4; ++g)
#pragma unroll
            for (int r2 = 0; r2 < 4; ++r2) {
                float sq0 = fmaf(-2.0f, acc0[g * 4 + r2], qi[0][g][r2] + qwjv.x);
                float sq1 = fmaf(-2.0f, acc1[g * 4 + r2], qi[1][g][r2] + qwjv.x);
                if (diag) {
                    float d0 = __builtin_amdgcn_sqrtf(fmaxf(sq0, 0.0f));
                    float d1 = __builtin_amdgcn_sqrtf(fmaxf(sq1, 0.0f));
                    la0 += fmaxf(d0 + wi[0][g][r2], 0.0f);
                    la1 += fmaxf(d1 + wi[1][g][r2], 0.0f);
                } else {
                    float d0 = __builtin_amdgcn_sqrtf(sq0);  // off-diag: sq >= ~0.9
                    float d1 = __builtin_amdgcn_sqrtf(sq1);
                    la0 += fmaxf(d0 + wi[0][g][r2], 0.0f);
                    la1 += fmaxf(d1 + wi[1][g][r2], 0.0f);
                    lb0 += fmaxf(d0 + qwjv.y, 0.0f);
                    lb1 += fmaxf(d1 + qwjv.y, 0.0f);
                }
            }

        __builtin_amdgcn_sched_barrier(0);
        __builtin_amdgcn_s_barrier();  // reads of cur buffers done before restage
        if (chA) apar ^= 1;
    }

    // block reduction + one atomic per block
    float local = (la0 + la1) + (lb0 + lb1);
#pragma unroll
    for (int m = 1; m < 64; m <<= 1) local += __shfl_xor(local, m);
    __syncthreads();
    float* sred = (float*)smem;
    if (lane == 0) sred[wave] = local;
    __syncthreads();
    if (tid == 0) {
        float t0 = (sred[0] + sred[1]) + (sred[2] + sred[3]);
        float t1 = (sred[4] + sred[5]) + (sred[6] + sred[7]);
        atomicAdd(out, (t0 + t1) * INV_DENOM);
    }
}

extern "C" void kernel_launch(void* const* d_in, const int* in_sizes, int n_in,
                              void* d_out, int out_size, void* d_ws, size_t ws_size,
                              hipStream_t stream) {
    const float* p = (const float*)d_in[0];  // [8192,128] f32
    const float* n = (const float*)d_in[1];  // [64,128] f32
    float* out = (float*)d_out;
    char* ws = (char*)d_ws;

    char*  pb    = ws;                        // 1 MB (8192 x 128 B fp8)
    float* qwarr = (float*)(ws + (1u << 20)); // 64 KB (8192 x float2 {q8, w})

    hipLaunchKernelGGL(rows_kernel, dim3(LP / 16), dim3(64), 0, stream, p, n, pb, qwarr,
                       out);
    hipLaunchKernelGGL(pair_kernel, dim3(NBLK), dim3(512), 0, stream, pb, qwarr, out);
}